// Round 8
// baseline (48.048 us; speedup 1.0000x reference)
//
#include <hip/hip_runtime.h>

// LSHAttention: reference returns ONLY sticker = argsort(buckets) [B,S] int32.
// B=4, S=4096, D=1024, NR=32, 64 buckets.
//
// k1: grid 1024 = (b:4, c32:128 -> 32 tok, ks:2 -> 512 k), 256 thr = 4 waves.
//     Thread tile 16 tok x 8 r x 16 k (acc[16][2] float4 = 128 VGPR, static).
//     Lane = (tok_t:2, r_t:4, kl:8); wave w; k-slice kappa = w*8+kl.
//     LDS (64 KB, double-buffered 2x(16KB Q + 16KB R)):
//       Q stored k-major in float4 units: [kq][tok'] with tok' = tok ^ (kq&7)
//       R stored [k][rq'] with rq' = rq ^ ((k>>2)&7)
//     -> hot-loop reads: qv 8 banks x 2-way, rv <=2-way/phase. 24 b128 per
//     512 FMA per thread-tile-step = 21.3 FMA/b128 (vs 10.7 in round 7).
//     Per K-tile (128 k): stage next tile (coalesced global f4), compute, bar.
//     Epilogue: shfl_xor(1) pair-reduce, 16-slice LDS dump, 256-thr sum -> P.
// k1c: sum 2 K-halves + argmax + 64-chunk hist (VERIFIED round 6, verbatim).
// k2/k3: scan + stable scatter (VERIFIED rounds 1-7, verbatim).

#define B_DIM 4
#define S_LEN 4096
#define D_DIM 1024
#define NRR 32
#define NBK 64
#define TMK 32                 // tokens per k1 block
#define NC32 (S_LEN / TMK)     // 128
#define KQ 2                   // K-split factor
#define KHALF (D_DIM / KQ)     // 512
#define KB 128                 // k per LDS tile
#define NTILE (KHALF / KB)     // 4
#define HCH 64                 // hist/scatter chunk
#define NCHUNK (S_LEN / HCH)   // 64
#define PSLICE (TMK * NRR)     // 1024 floats per partial slice

#define Q_ELEM(q, kk) ((kk) == 0 ? (q).x : (kk) == 1 ? (q).y : (kk) == 2 ? (q).z : (q).w)
#define FMA4(A, S, B)                                                        \
    (A).x = fmaf((S), (B).x, (A).x); (A).y = fmaf((S), (B).y, (A).y);        \
    (A).z = fmaf((S), (B).z, (A).z); (A).w = fmaf((S), (B).w, (A).w);

__global__ __launch_bounds__(256, 2) void k1_gemm(
    const float* __restrict__ Q, const float* __restrict__ R,
    float4* __restrict__ P4)
{
    __shared__ float4 smem[4096];   // [0,1024): qbuf0 [1024,2048): qbuf1
                                    // [2048,3072): rbuf0 [3072,4096): rbuf1
                                    // whole thing reused as red[16][256] at end
    const int bid = blockIdx.x;
    const int ks  = bid & 1;
    const int c32 = (bid >> 1) & (NC32 - 1);
    const int b   = bid >> 8;

    const int t = threadIdx.x;
    const int w = t >> 6;
    const int lane = t & 63;
    const int tok_t = lane >> 5;        // 0..1 (16 tokens each)
    const int r_t = (lane >> 3) & 3;    // 0..3 (8 r each)
    const int kl = lane & 7;            // k-split low bits
    const int kappa = w * 8 + kl;       // 0..31: thread k-quad index per tile

    const float4* Qg4 = reinterpret_cast<const float4*>(
        Q + ((size_t)b * S_LEN + c32 * TMK) * D_DIM);     // row stride 256 f4
    const float4* Rg4 = reinterpret_cast<const float4*>(
        R + (size_t)b * D_DIM * NRR);                     // row stride 8 f4

    // hot-loop constant indices
    const int qbase = kappa * 32 + tok_t * 16;            // + (j ^ kl)
    const int rbase = kappa * 32;                         // (kappa*4+kk)*8 = kappa*32 + kk*8
    const int rsw0 = (r_t * 2 + 0) ^ kl;
    const int rsw1 = (r_t * 2 + 1) ^ kl;

    float4 acc[16][2];
#pragma unroll
    for (int j = 0; j < 16; ++j) {
        acc[j][0] = make_float4(0.f, 0.f, 0.f, 0.f);
        acc[j][1] = make_float4(0.f, 0.f, 0.f, 0.f);
    }

#define STAGE(TAU, D)                                                         \
    {                                                                         \
        const int kf4 = ks * (KHALF / 4) + (TAU) * (KB / 4);                  \
        float4 qs[4], rs[4];                                                  \
        _Pragma("unroll")                                                     \
        for (int i = 0; i < 4; ++i) {                                         \
            const int f = t + 256 * i;                                        \
            qs[i] = Qg4[(size_t)(f >> 5) * 256 + kf4 + (f & 31)];             \
        }                                                                     \
        _Pragma("unroll")                                                     \
        for (int i = 0; i < 4; ++i) {                                         \
            const int f = t + 256 * i;                                        \
            rs[i] = Rg4[(size_t)(ks * KHALF + (TAU) * KB + (f >> 3)) * 8 + (f & 7)]; \
        }                                                                     \
        float4* qb = smem + (D) * 1024;                                       \
        float4* rb = smem + 2048 + (D) * 1024;                                \
        _Pragma("unroll")                                                     \
        for (int i = 0; i < 4; ++i) {                                         \
            const int f = t + 256 * i;                                        \
            const int tok = f >> 5, kq = f & 31;                              \
            qb[kq * 32 + (tok ^ (kq & 7))] = qs[i];                           \
        }                                                                     \
        _Pragma("unroll")                                                     \
        for (int i = 0; i < 4; ++i) {                                         \
            const int f = t + 256 * i;                                        \
            const int k = f >> 3, rq = f & 7;                                 \
            rb[k * 8 + (rq ^ ((k >> 2) & 7))] = rs[i];                        \
        }                                                                     \
    }

    STAGE(0, 0)
    __syncthreads();

    for (int tau = 0; tau < NTILE; ++tau) {
        if (tau + 1 < NTILE) {
            const int d = (tau + 1) & 1;
            STAGE(tau + 1, d)
        }
        // ---- compute on buffer tau&1 ----
        {
            const float4* qb = smem + (tau & 1) * 1024;
            const float4* rb = smem + 2048 + (tau & 1) * 1024;
            float4 rv[4][2];
#pragma unroll
            for (int kk = 0; kk < 4; ++kk) {
                rv[kk][0] = rb[rbase + kk * 8 + rsw0];
                rv[kk][1] = rb[rbase + kk * 8 + rsw1];
            }
#pragma unroll
            for (int tq = 0; tq < 4; ++tq) {
                float4 qv[4];
#pragma unroll
                for (int jj = 0; jj < 4; ++jj)
                    qv[jj] = qb[qbase + ((tq * 4 + jj) ^ kl)];
#pragma unroll
                for (int jj = 0; jj < 4; ++jj) {
#pragma unroll
                    for (int kk = 0; kk < 4; ++kk) {
                        const float s = Q_ELEM(qv[jj], kk);
                        FMA4(acc[tq * 4 + jj][0], s, rv[kk][0]);
                        FMA4(acc[tq * 4 + jj][1], s, rv[kk][1]);
                    }
                }
            }
        }
        __syncthreads();
    }
#undef STAGE

    // ---- pair-reduce over kl bit 0 (lanes kl, kl^1 share (tok_t, r_t)) ----
#pragma unroll
    for (int j = 0; j < 16; ++j)
#pragma unroll
        for (int h = 0; h < 2; ++h) {
            acc[j][h].x += __shfl_xor(acc[j][h].x, 1, 64);
            acc[j][h].y += __shfl_xor(acc[j][h].y, 1, 64);
            acc[j][h].z += __shfl_xor(acc[j][h].z, 1, 64);
            acc[j][h].w += __shfl_xor(acc[j][h].w, 1, 64);
        }

    // ---- dump 16 slices (w*4 + kl/2) of [32 tok][8 rq] into smem overlay ----
    if ((kl & 1) == 0) {
        const int slice = w * 4 + (kl >> 1);   // 0..15
#pragma unroll
        for (int j = 0; j < 16; ++j)
#pragma unroll
            for (int h = 0; h < 2; ++h)
                smem[slice * 256 + (tok_t * 16 + j) * 8 + (r_t * 2 + h)] = acc[j][h];
    }
    __syncthreads();

    // ---- final sum over 16 slices; coalesced P store ----
    {
        float4 s = smem[t];
#pragma unroll
        for (int sl = 1; sl < 16; ++sl) {
            const float4 v = smem[sl * 256 + t];
            s.x += v.x; s.y += v.y; s.z += v.z; s.w += v.w;
        }
        P4[(((size_t)b * NC32 + c32) * KQ + ks) * 256 + t] = s;
    }
}

// 256 blocks = (b, 64-token chunk): sum 2 K-halves, argmax, bucket, hist.
// (verified round 6, verbatim)
__global__ __launch_bounds__(256) void k1c_combine(
    const float* __restrict__ P,
    int* __restrict__ buckets, int* __restrict__ hist)
{
    __shared__ float xs[HCH][NRR + 1];
    __shared__ int cnt[NBK];

    const int bid = blockIdx.x;
    const int b = bid >> 6;
    const int h = bid & 63;
    const int t = threadIdx.x;

#pragma unroll
    for (int i = 0; i < 8; ++i) {
        const int idx = t + 256 * i;           // 0..2047 = 64 tok x 32 r
        const int tok = idx >> 5, r = idx & 31;
        const int c32 = h * 2 + (tok >> 5);
        const int tokin = tok & 31;
        const size_t base = (((size_t)b * NC32 + c32) * KQ) * PSLICE
                          + (size_t)tokin * NRR + r;
        xs[tok][r] = P[base] + P[base + PSLICE];
    }
    if (t < NBK) cnt[t] = 0;
    __syncthreads();

    if (t < HCH) {
        // argmax(concat[xR,-xR]) with first-occurrence tie-break
        float m1 = xs[t][0]; int i1 = 0;
        float m2 = m1;       int i2 = 0;
#pragma unroll
        for (int r = 1; r < NRR; ++r) {
            const float v = xs[t][r];
            if (v > m1) { m1 = v; i1 = r; }
            if (v < m2) { m2 = v; i2 = r; }
        }
        const int bk = (m1 >= -m2) ? i1 : (NRR + i2);
        buckets[(size_t)b * S_LEN + h * HCH + t] = bk;
        atomicAdd(&cnt[bk], 1);
    }
    __syncthreads();
    if (t < NBK) hist[((size_t)b * NCHUNK + h) * NBK + t] = cnt[t];
}

// One block, 256 threads: thread = (batch b = t/64, bucket bk = t%64).
__global__ __launch_bounds__(256) void k2_scan(
    const int* __restrict__ hist, int* __restrict__ chunkOffset)
{
    const int t = threadIdx.x;
    const int b = t >> 6;
    const int bk = t & 63;
    const int lane = t & 63;

    int total = 0;
    for (int c = 0; c < NCHUNK; ++c)
        total += hist[((size_t)b * NCHUNK + c) * NBK + bk];

    int incl = total;
#pragma unroll
    for (int off = 1; off < 64; off <<= 1) {
        int n = __shfl_up(incl, off, 64);
        if (lane >= off) incl += n;
    }
    int run = incl - total;   // exclusive prefix over buckets = bucketStart

    for (int c = 0; c < NCHUNK; ++c) {
        int h = hist[((size_t)b * NCHUNK + c) * NBK + bk];
        chunkOffset[((size_t)b * NCHUNK + c) * NBK + bk] = run;
        run += h;
    }
}

// Stable scatter: wave = 64 consecutive tokens (one chunk).
__global__ __launch_bounds__(256) void k3_scatter(
    const int* __restrict__ buckets, const int* __restrict__ chunkOffset,
    int* __restrict__ out)
{
    const int gid = blockIdx.x * 256 + threadIdx.x;  // 0..16383
    const int b = gid >> 12;
    const int s = gid & (S_LEN - 1);
    const int chunk = s >> 6;
    const int lane = threadIdx.x & 63;

    const int bk = buckets[gid];

    unsigned long long m = ~0ull;
#pragma unroll
    for (int i = 0; i < 6; ++i) {
        unsigned long long bi = __ballot((bk >> i) & 1);
        m &= ((bk >> i) & 1) ? bi : ~bi;
    }
    int rank = __popcll(m & ((1ull << lane) - 1ull));

    int pos = chunkOffset[((size_t)b * NCHUNK + chunk) * NBK + bk] + rank;
    out[(size_t)b * S_LEN + pos] = s;
}

extern "C" void kernel_launch(void* const* d_in, const int* in_sizes, int n_in,
                              void* d_out, int out_size, void* d_ws, size_t ws_size,
                              hipStream_t stream) {
    const float* Q = (const float*)d_in[0];
    // d_in[1] = key, d_in[2] = value: dead code in the reference, never read.
    const float* R = (const float*)d_in[3];

    float* P          = (float*)d_ws;    // 4*128*2*1024 floats = 4 MB
    int* buckets      = (int*)(P + (size_t)B_DIM * NC32 * KQ * PSLICE);
    int* hist         = buckets + B_DIM * S_LEN;
    int* chunkOffset  = hist + B_DIM * NCHUNK * NBK;

    k1_gemm    <<<B_DIM * NC32 * KQ, 256, 0, stream>>>(Q, R, (float4*)P);
    k1c_combine<<<B_DIM * NCHUNK,    256, 0, stream>>>(P, buckets, hist);
    k2_scan    <<<1,                 256, 0, stream>>>(hist, chunkOffset);
    k3_scatter <<<(B_DIM * S_LEN) / 256, 256, 0, stream>>>(buckets, chunkOffset, (int*)d_out);
}